// Round 4
// baseline (139.875 us; speedup 1.0000x reference)
//
#include <hip/hip_runtime.h>
#include <hip/hip_fp8.h>

#define BB 8
#define NN 4096
#define MM 4096
#define DD 128

typedef float f32x4  __attribute__((ext_vector_type(4)));
typedef float f32x16 __attribute__((ext_vector_type(16)));
typedef int   i32x4  __attribute__((ext_vector_type(4)));
typedef int   i32x8  __attribute__((ext_vector_type(8)));

// ---------------------------------------------------------------------------
// R24: kill the in-loop barriers, double the TLP. R23 evidence: main=47us,
// Occ 25% (8 waves/CU), VALU 56, Mfma 14 -> per-batch ~3.5k cyc vs ~500 cyc
// compute floor: the per-batch __syncthreads (implicit vmcnt(0)) drains the
// next-batch prefetch every iteration with only 2 blocks/CU of cover.
// New main: 1024 blocks x 512 threads (8 waves; 256n x 64m per block).
//   - ALL 8 batches of y-frags (64KB) staged in the PROLOGUE via
//     global_load_lds (1 load/wave/batch), ONE barrier, then the 8-batch
//     loop has ZERO __syncthreads: x stays register-dbuf'd and the compiler
//     waits only on real consumers (no forced vmcnt(0) drain).
//   - LDS ~76KB -> 2 blocks/CU = 16 waves/CU (50% occ), 2x R23's TLP.
//   - y L2 traffic halves again (131->66MB); x unchanged 256MB; per-XCD
//     working set still 3MB < 4MB XCD L2 (balanced patch kept).
// Staging source-swizzle re-derived for 8 waves: chunk c=wave ->
// (t,i,lh)=(c>>2,(c>>1)&1,c&1); lane l -> l31*32+(l>>5)*16. Read side
// byte-identical to R22/R23's verified dense layout (absmax 0).
//
// R19-23 retained: fragment-ordered fp8, HALF-norms + negated y (acc=sq/2),
// mfma_scale_f32_32x32x64_f8f6f4 identity scale, coalesced prep.
// LESSONS: merged finalize regresses (R11/12/15/16); cooperative launch
// fails (R14); prep transport not the gap (R21); per-batch barriers cost
// ~2x at low occupancy (R23).
// ---------------------------------------------------------------------------

typedef const __attribute__((address_space(1))) unsigned int* gas_ptr;
typedef __attribute__((address_space(3))) unsigned int* las_ptr;
static __device__ __forceinline__ void gload_lds16(const unsigned char* g,
                                                   unsigned char* l) {
    __builtin_amdgcn_global_load_lds((gas_ptr)g, (las_ptr)l, 16, 0, 0);
}

// Prep v2 (R21, unchanged): 2048 blocks x 256 threads, one 32-row fragment
// group (4KB) per block; coalesced reads -> cvt -> LDS permute -> coalesced
// 16B stores. Also inits fwd/bsum/fsum/counter and writes half-norms.
__global__ __launch_bounds__(256)
void prep_all(const float* __restrict__ x, const float* __restrict__ y,
              unsigned char* __restrict__ xq, unsigned char* __restrict__ yq,
              float* __restrict__ x2, float* __restrict__ y2,
              unsigned int* __restrict__ fwd, float* __restrict__ bsum,
              float* __restrict__ fsum, unsigned int* __restrict__ counter) {
    __shared__ i32x4 lbuf[256];  // 4 KB fragment-ordered staging

    const int tid  = threadIdx.x;
    const int g    = blockIdx.x;
    const int gtid = g * 256 + tid;
    if (gtid < BB * MM) fwd[gtid] = 0x7f800000u;  // +inf bits
    if (gtid == 0) { *bsum = 0.0f; *fsum = 0.0f; *counter = 0u; }

    const int rl = tid >> 3;   // row within group (0..31)
    const int c  = tid & 7;    // 16-float chunk within row (0..7)

    const float* src;
    unsigned char* dst;
    float* sq;
    float sgn;
    int row;
    if (g < 1024) {
        src = x; dst = xq + (size_t)g * 4096; sq = x2; sgn = 1.0f;
        row = g * 32 + rl;
    } else {
        src = y; dst = yq + (size_t)(g - 1024) * 4096; sq = y2; sgn = -1.0f;
        row = (g - 1024) * 32 + rl;
    }

    const f32x4* base = (const f32x4*)(src + (size_t)row * DD + c * 16);
    f32x4 v[4];
    #pragma unroll
    for (int j = 0; j < 4; ++j) v[j] = base[j];

    float s = 0.0f;
    #pragma unroll
    for (int j = 0; j < 4; ++j)
        s += v[j].x * v[j].x + v[j].y * v[j].y + v[j].z * v[j].z + v[j].w * v[j].w;

    i32x4 d;
    #pragma unroll
    for (int j = 0; j < 4; ++j) {
        unsigned int dj = (unsigned int)__builtin_amdgcn_cvt_pk_fp8_f32(
            sgn * v[j].x, sgn * v[j].y, 0, false);
        dj = (unsigned int)__builtin_amdgcn_cvt_pk_fp8_f32(
            sgn * v[j].z, sgn * v[j].w, (int)dj, true);
        d[j] = (int)dj;
    }

    const int lds_off = (c >> 2) * 2048 + ((c >> 1) & 1) * 1024
                      + rl * 32 + (c & 1) * 16;
    *(i32x4*)((char*)lbuf + lds_off) = d;

    #pragma unroll
    for (int m = 4; m; m >>= 1) s += __shfl_xor(s, m, 64);
    if (c == 0) sq[row] = 0.5f * s;

    __syncthreads();
    *(i32x4*)(dst + (size_t)tid * 16) = lbuf[tid];
}

// ---------------------------------------------------------------------------
// Main v4: 1024 blocks (256n x 64m), 8 waves of 32n x 64m, barrier-free loop.
// ---------------------------------------------------------------------------
__global__ __launch_bounds__(512, 4)
void chamfer_main(const unsigned char* __restrict__ xq, const unsigned char* __restrict__ yq,
                  const float* __restrict__ x2, const float* __restrict__ y2,
                  unsigned int* __restrict__ fwd, float* __restrict__ bpart) {
    __shared__ float x2s[BB][256];            // 8 KB
    __shared__ float y2s[BB][64];             // 2 KB
    __shared__ unsigned int fbuf[BB][64];     // 2 KB
    __shared__ unsigned char ybuf[BB][8192];  // 64 KB: ALL batches of y-frags
    __shared__ float red[8];

    const int tid   = threadIdx.x;
    const int lane  = tid & 63;
    const int wave  = tid >> 6;    // 0..7
    const int lhalf = lane >> 5;
    const int l31   = lane & 31;

    const int id  = blockIdx.x;
    const int xcd = id & 7;
    const int j   = id >> 3;                   // 0..127
    const int nb  = (xcd >> 1) * 4 + (j & 3);  // 0..15  (256 n each)
    const int mb  = (xcd & 1) * 32 + (j >> 2); // 0..63  (64 m each)
    const int n0b = nb * 256;
    const int n0w = n0b + wave * 32;
    const int m0  = mb * 64;

    // x fragment base (per-wave registers)
    const size_t laneoff = (size_t)lhalf * 1024 + (size_t)l31 * 32;
    const unsigned char* xbase = xq + (size_t)(n0w >> 5) * 4096 + laneoff;

    // y staging, source-swizzled so LDS is dense (gload_lds writes linear):
    // wave = chunk c -> (t,i,lh) = (c>>2,(c>>1)&1,c&1); lane -> l31*32+hh*16
    const size_t ysw = (size_t)(wave >> 2) * 4096 + (size_t)((wave >> 1) & 1) * 2048
                     + (size_t)(wave & 1) * 1024 + (size_t)l31 * 32
                     + (size_t)lhalf * 16;
    const unsigned char* ybase = yq + (size_t)mb * 8192 + ysw;

    // prologue: stage ALL 8 batches of y (1 gload_lds per wave per batch)
    #pragma unroll
    for (int b = 0; b < BB; ++b)
        gload_lds16(ybase + ((size_t)b << 19), &ybuf[b][wave * 1024]);

    i32x4 fx[2][2][2];  // [buf][instr(K64)][16B half]
    auto loadx = [&](int b, int s) {
        const unsigned char* xb = xbase + ((size_t)b << 19);
        #pragma unroll
        for (int i = 0; i < 2; ++i)
            #pragma unroll
            for (int hh = 0; hh < 2; ++hh)
                fx[s][i][hh] = *(const i32x4*)(xb + i * 2048 + hh * 16);
    };
    loadx(0, 0);

    for (int i = tid; i < BB * 256; i += 512)
        x2s[i >> 8][i & 255] = x2[(size_t)(i >> 8) * NN + n0b + (i & 255)];
    {
        int i = tid;  // exactly BB*64 = 512 items
        y2s[i >> 6][i & 63] = y2[(size_t)(i >> 6) * MM + m0 + (i & 63)];
        ((unsigned int*)fbuf)[i] = 0x7f800000u;
    }
    __syncthreads();  // the ONLY pre-loop barrier (drains all staging)

    const float INF = __builtin_inff();
    float bmin[2][16];  // [m-tile][reg] running min of acc = sq/2
    #pragma unroll
    for (int t = 0; t < 2; ++t)
        #pragma unroll
        for (int r = 0; r < 16; ++r) bmin[t][r] = INF;

    const int rb0 = lhalf * 1024 + l31 * 16;  // dense y read base

    #pragma unroll 2
    for (int b = 0; b < BB; ++b) {
        const int cur = b & 1;
        if (b < BB - 1) loadx(b + 1, cur ^ 1);  // reg-dbuf, no barrier needed

        // acc seeds: (x2+y2)/2 -> MFMA (neg-y fp8) yields acc = sq/2
        // C/D: col = l31, row = (r&3) + 8*(r>>2) + 4*lhalf
        float y2v[2];
        y2v[0] = y2s[b][l31];
        y2v[1] = y2s[b][32 + l31];
        f32x16 acc[2];
        #pragma unroll
        for (int q = 0; q < 4; ++q) {
            f32x4 xv = *(const f32x4*)&x2s[b][wave * 32 + lhalf * 4 + q * 8];
            #pragma unroll
            for (int t = 0; t < 2; ++t)
                #pragma unroll
                for (int e = 0; e < 4; ++e)
                    acc[t][q * 4 + e] = xv[e] + y2v[t];
        }

        #pragma unroll
        for (int i = 0; i < 2; ++i) {
            i32x8 av = __builtin_shufflevector(fx[cur][i][0], fx[cur][i][1],
                                               0, 1, 2, 3, 4, 5, 6, 7);
            #pragma unroll
            for (int t = 0; t < 2; ++t) {
                const unsigned char* yb = &ybuf[b][t * 4096 + i * 2048 + rb0];
                i32x4 lo = *(const i32x4*)(yb);
                i32x4 hi = *(const i32x4*)(yb + 512);
                i32x8 bv = __builtin_shufflevector(lo, hi, 0, 1, 2, 3, 4, 5, 6, 7);
                acc[t] = __builtin_amdgcn_mfma_scale_f32_32x32x64_f8f6f4(
                    av, bv, acc[t], 0, 0, 0, 127, 0, 127);
            }
        }

        // epilogue: pure fmin (acc IS sq/2)
        float fm[2] = {INF, INF};
        #pragma unroll
        for (int t = 0; t < 2; ++t)
            #pragma unroll
            for (int r = 0; r < 16; ++r) {
                bmin[t][r] = fminf(bmin[t][r], acc[t][r]);
                fm[t]      = fminf(fm[t], acc[t][r]);
            }
        #pragma unroll
        for (int t = 0; t < 2; ++t)
            atomicMin(&fbuf[b][t * 32 + l31],
                      __float_as_uint(fmaxf(fm[t], 0.0f)));
    }
    __syncthreads();  // fbuf atomics from all waves complete

    // flush forward mins (values are sq/2; finalize applies the 2x)
    {
        int i = tid;  // exactly BB*64 = 512 items
        atomicMin(&fwd[(size_t)(i >> 6) * MM + m0 + (i & 63)], fbuf[i >> 6][i & 63]);
    }

    // backward: sqrt(2 * clamp(min sq/2)), block-reduce, one store/block
    float s = 0.0f;
    #pragma unroll
    for (int t = 0; t < 2; ++t)
        #pragma unroll
        for (int r = 0; r < 16; ++r)
            s += sqrtf(2.0f * fmaxf(bmin[t][r], 0.0f));
    #pragma unroll
    for (int off = 32; off; off >>= 1) s += __shfl_down(s, off, 64);
    if (lane == 0) red[wave] = s;
    __syncthreads();
    if (tid == 0)
        bpart[id] = red[0] + red[1] + red[2] + red[3]
                  + red[4] + red[5] + red[6] + red[7];
}

// Finalize: 32 blocks x 256 threads. fwd holds min sq/2 -> dist = sqrt(2v).
__global__ __launch_bounds__(256)
void finalize_kernel(const unsigned int* __restrict__ fwd,
                     const float* __restrict__ bpart,
                     float* __restrict__ bsum, float* __restrict__ fsum,
                     unsigned int* __restrict__ counter, float* __restrict__ out) {
    __shared__ float redf[4], redb[4];
    __shared__ int isLast;
    const int tid = threadIdx.x, lane = tid & 63, wave = tid >> 6;
    const int gtid = blockIdx.x * 256 + tid;
    uint4 u = ((const uint4*)fwd)[gtid];
    float sf = sqrtf(2.0f * __uint_as_float(u.x)) + sqrtf(2.0f * __uint_as_float(u.y)) +
               sqrtf(2.0f * __uint_as_float(u.z)) + sqrtf(2.0f * __uint_as_float(u.w));
    float sb = (gtid < 1024) ? bpart[gtid] : 0.0f;   // 1024 main blocks now
    #pragma unroll
    for (int off = 32; off; off >>= 1) {
        sf += __shfl_down(sf, off, 64);
        sb += __shfl_down(sb, off, 64);
    }
    if (lane == 0) { redf[wave] = sf; redb[wave] = sb; }
    __syncthreads();
    if (tid == 0) {
        atomicAdd(fsum, redf[0] + redf[1] + redf[2] + redf[3]);
        atomicAdd(bsum, redb[0] + redb[1] + redb[2] + redb[3]);
        __threadfence();
        unsigned int c = atomicAdd(counter, 1u);
        isLast = (c == gridDim.x - 1) ? 1 : 0;
        if (isLast) {
            __threadfence();
            float fs = __hip_atomic_load(fsum, __ATOMIC_RELAXED,
                                         __HIP_MEMORY_SCOPE_AGENT);
            float bs = __hip_atomic_load(bsum, __ATOMIC_RELAXED,
                                         __HIP_MEMORY_SCOPE_AGENT);
            out[0] = fs / (float)(BB * MM) + bs / ((float)NN * (float)MM);
        }
    }
}

extern "C" void kernel_launch(void* const* d_in, const int* in_sizes, int n_in,
                              void* d_out, int out_size, void* d_ws, size_t ws_size,
                              hipStream_t stream) {
    const float* x = (const float*)d_in[0];  // (B,N,D)
    const float* y = (const float*)d_in[1];  // (B,M,D)
    float* out = (float*)d_out;

    char* w = (char*)d_ws;
    unsigned char* xq = (unsigned char*)(w);               // 4 MB fp8 (frag order)
    unsigned char* yq = (unsigned char*)(w + 4194304);     // 4 MB fp8, NEGATED
    float*    x2 = (float*)(w + 8388608);                  // 128 KB (x2/2)
    float*    y2 = (float*)(w + 8519680);                  // 128 KB (y2/2)
    unsigned int* fwd = (unsigned int*)(w + 8650752);      // 128 KB (min sq/2)
    float*    bpart = (float*)(w + 8781824);               // 4 KB (1024 blocks)
    float*    bsum = (float*)(w + 8798208);                // 4 B
    float*    fsum = (float*)(w + 8798212);                // 4 B
    unsigned int* counter = (unsigned int*)(w + 8798216);  // 4 B

    prep_all<<<2048, 256, 0, stream>>>(x, y, xq, yq, x2, y2,
                                       fwd, bsum, fsum, counter);
    chamfer_main<<<1024, 512, 0, stream>>>(xq, yq, x2, y2, fwd, bpart);
    finalize_kernel<<<32, 256, 0, stream>>>(fwd, bpart, bsum, fsum, counter, out);
}

// Round 5
// 113.845 us; speedup vs baseline: 1.2286x; 1.2286x over previous
//
#include <hip/hip_runtime.h>
#include <hip/hip_fp8.h>

#define BB 8
#define NN 4096
#define MM 4096
#define DD 128

typedef float f32x4  __attribute__((ext_vector_type(4)));
typedef float f32x16 __attribute__((ext_vector_type(16)));
typedef int   i32x4  __attribute__((ext_vector_type(4)));
typedef int   i32x8  __attribute__((ext_vector_type(8)));

// ---------------------------------------------------------------------------
// R25: R24's barrier-free idea at R23's proven 256-thread shape. R24 failure
// mode (counters): WRITE_SIZE 4.2->118MB, FETCH 12.7->39MB, VGPR_Count=64,
// first dispatch 165us -> REGISTER SPILLS to scratch. The 512-thread/8-wave
// block left only ~128 unified VGPR+AGPR per wave vs ~160 live.
// Fix: 256-thread blocks (4 waves), LDS 72KB -> 2 blocks/CU = 8 waves/CU =
// 2 waves/SIMD -> per-wave budget 256 VGPR. __launch_bounds__(256,2)
// declares exactly that; ~110-140 used, zero spills.
// Structure: prologue stages ALL 8 batches of y-frags (64KB, 16 gload_lds
// per wave, R23's byte-identical verified source swizzle), ONE barrier,
// then the 8-batch loop has ZERO __syncthreads (R23's diagnosed per-iter
// vmcnt(0) drain gone); x stays register-dbuf'd.
//
// R19-23 retained: fragment-ordered fp8 (absmax 0), HALF-norms + negated y
// (acc=sq/2), mfma_scale_f32_32x32x64_f8f6f4 identity scale 127, balanced
// per-XCD patch (3MB < 4MB XCD L2), coalesced LDS-staged prep.
// LESSONS: merged finalize regresses (R11/12/15/16); cooperative launch
// fails (R14); prep transport not the gap (R21); per-batch barriers cost
// ~2x at low occ (R23); 8-wave blocks spill with this state size (R24).
// ---------------------------------------------------------------------------

typedef const __attribute__((address_space(1))) unsigned int* gas_ptr;
typedef __attribute__((address_space(3))) unsigned int* las_ptr;
static __device__ __forceinline__ void gload_lds16(const unsigned char* g,
                                                   unsigned char* l) {
    __builtin_amdgcn_global_load_lds((gas_ptr)g, (las_ptr)l, 16, 0, 0);
}

// Prep v2 (R21, unchanged): 2048 blocks x 256 threads, one 32-row fragment
// group (4KB) per block; coalesced reads -> cvt -> LDS permute -> coalesced
// 16B stores. Also inits fwd/bsum/fsum/counter and writes half-norms.
__global__ __launch_bounds__(256)
void prep_all(const float* __restrict__ x, const float* __restrict__ y,
              unsigned char* __restrict__ xq, unsigned char* __restrict__ yq,
              float* __restrict__ x2, float* __restrict__ y2,
              unsigned int* __restrict__ fwd, float* __restrict__ bsum,
              float* __restrict__ fsum, unsigned int* __restrict__ counter) {
    __shared__ i32x4 lbuf[256];  // 4 KB fragment-ordered staging

    const int tid  = threadIdx.x;
    const int g    = blockIdx.x;
    const int gtid = g * 256 + tid;
    if (gtid < BB * MM) fwd[gtid] = 0x7f800000u;  // +inf bits
    if (gtid == 0) { *bsum = 0.0f; *fsum = 0.0f; *counter = 0u; }

    const int rl = tid >> 3;   // row within group (0..31)
    const int c  = tid & 7;    // 16-float chunk within row (0..7)

    const float* src;
    unsigned char* dst;
    float* sq;
    float sgn;
    int row;
    if (g < 1024) {
        src = x; dst = xq + (size_t)g * 4096; sq = x2; sgn = 1.0f;
        row = g * 32 + rl;
    } else {
        src = y; dst = yq + (size_t)(g - 1024) * 4096; sq = y2; sgn = -1.0f;
        row = (g - 1024) * 32 + rl;
    }

    const f32x4* base = (const f32x4*)(src + (size_t)row * DD + c * 16);
    f32x4 v[4];
    #pragma unroll
    for (int j = 0; j < 4; ++j) v[j] = base[j];

    float s = 0.0f;
    #pragma unroll
    for (int j = 0; j < 4; ++j)
        s += v[j].x * v[j].x + v[j].y * v[j].y + v[j].z * v[j].z + v[j].w * v[j].w;

    i32x4 d;
    #pragma unroll
    for (int j = 0; j < 4; ++j) {
        unsigned int dj = (unsigned int)__builtin_amdgcn_cvt_pk_fp8_f32(
            sgn * v[j].x, sgn * v[j].y, 0, false);
        dj = (unsigned int)__builtin_amdgcn_cvt_pk_fp8_f32(
            sgn * v[j].z, sgn * v[j].w, (int)dj, true);
        d[j] = (int)dj;
    }

    const int lds_off = (c >> 2) * 2048 + ((c >> 1) & 1) * 1024
                      + rl * 32 + (c & 1) * 16;
    *(i32x4*)((char*)lbuf + lds_off) = d;

    #pragma unroll
    for (int m = 4; m; m >>= 1) s += __shfl_xor(s, m, 64);
    if (c == 0) sq[row] = 0.5f * s;

    __syncthreads();
    *(i32x4*)(dst + (size_t)tid * 16) = lbuf[tid];
}

// ---------------------------------------------------------------------------
// Main v5: 2048 blocks (128n x 64m), 4 waves of 32n x 64m, all-y-staged
// prologue, barrier-free batch loop, big VGPR budget.
// ---------------------------------------------------------------------------
__global__ __launch_bounds__(256, 2)
void chamfer_main(const unsigned char* __restrict__ xq, const unsigned char* __restrict__ yq,
                  const float* __restrict__ x2, const float* __restrict__ y2,
                  unsigned int* __restrict__ fwd, float* __restrict__ bpart) {
    __shared__ float x2s[BB][128];            // 4 KB
    __shared__ float y2s[BB][64];             // 2 KB
    __shared__ unsigned int fbuf[BB][64];     // 2 KB
    __shared__ unsigned char ybuf[BB][8192];  // 64 KB: ALL batches of y-frags
    __shared__ float red[4];

    const int tid   = threadIdx.x;
    const int lane  = tid & 63;
    const int wave  = tid >> 6;    // 0..3
    const int lhalf = lane >> 5;
    const int l31   = lane & 31;

    const int id  = blockIdx.x;
    const int xcd = id & 7;
    const int j   = id >> 3;                   // 0..255
    const int nb  = (xcd >> 1) * 8 + (j & 7);  // 0..31  (128 n each)
    const int mb  = (xcd & 1) * 32 + (j >> 3); // 0..63  (64 m each)
    const int n0b = nb * 128;
    const int n0w = n0b + wave * 32;
    const int m0  = mb * 64;

    // x fragment base (per-wave registers)
    const size_t laneoff = (size_t)lhalf * 1024 + (size_t)l31 * 32;
    const unsigned char* xbase = xq + (size_t)(n0w >> 5) * 4096 + laneoff;

    // y staging, source-swizzled so LDS is dense (R23-verified formula):
    // wave w stages chunk w of group 0 and chunk w of group 1.
    const size_t ysw = (size_t)(wave >> 1) * 2048 + (size_t)(wave & 1) * 1024
                     + ((size_t)lhalf << 4) + (size_t)l31 * 32;
    const unsigned char* ybase = yq + (size_t)mb * 8192 + ysw;

    // prologue: stage ALL 8 batches of y (2 gload_lds per wave per batch)
    #pragma unroll
    for (int b = 0; b < BB; ++b) {
        const unsigned char* gsrc = ybase + ((size_t)b << 19);
        gload_lds16(gsrc,        &ybuf[b][wave * 1024]);
        gload_lds16(gsrc + 4096, &ybuf[b][4096 + wave * 1024]);
    }

    i32x4 fx[2][2][2];  // [buf][instr(K64)][16B half]
    auto loadx = [&](int b, int s) {
        const unsigned char* xb = xbase + ((size_t)b << 19);
        #pragma unroll
        for (int i = 0; i < 2; ++i)
            #pragma unroll
            for (int hh = 0; hh < 2; ++hh)
                fx[s][i][hh] = *(const i32x4*)(xb + i * 2048 + hh * 16);
    };
    loadx(0, 0);

    for (int i = tid; i < BB * 128; i += 256)
        x2s[i >> 7][i & 127] = x2[(size_t)(i >> 7) * NN + n0b + (i & 127)];
    for (int i = tid; i < BB * 64; i += 256) {
        y2s[i >> 6][i & 63] = y2[(size_t)(i >> 6) * MM + m0 + (i & 63)];
        ((unsigned int*)fbuf)[i] = 0x7f800000u;
    }
    __syncthreads();  // the ONLY barrier before the loop (drains staging)

    const float INF = __builtin_inff();
    float bmin[2][16];  // [m-tile][reg] running min of acc = sq/2
    #pragma unroll
    for (int t = 0; t < 2; ++t)
        #pragma unroll
        for (int r = 0; r < 16; ++r) bmin[t][r] = INF;

    const int rb0 = lhalf * 1024 + l31 * 16;  // dense y read base

    #pragma unroll 2
    for (int b = 0; b < BB; ++b) {
        const int cur = b & 1;
        if (b < BB - 1) loadx(b + 1, cur ^ 1);  // reg-dbuf, no barrier needed

        // acc seeds: (x2+y2)/2 -> MFMA (neg-y fp8) yields acc = sq/2
        // C/D: col = l31, row = (r&3) + 8*(r>>2) + 4*lhalf
        float y2v[2];
        y2v[0] = y2s[b][l31];
        y2v[1] = y2s[b][32 + l31];
        f32x16 acc[2];
        #pragma unroll
        for (int q = 0; q < 4; ++q) {
            f32x4 xv = *(const f32x4*)&x2s[b][wave * 32 + lhalf * 4 + q * 8];
            #pragma unroll
            for (int t = 0; t < 2; ++t)
                #pragma unroll
                for (int e = 0; e < 4; ++e)
                    acc[t][q * 4 + e] = xv[e] + y2v[t];
        }

        #pragma unroll
        for (int i = 0; i < 2; ++i) {
            i32x8 av = __builtin_shufflevector(fx[cur][i][0], fx[cur][i][1],
                                               0, 1, 2, 3, 4, 5, 6, 7);
            #pragma unroll
            for (int t = 0; t < 2; ++t) {
                const unsigned char* yb = &ybuf[b][t * 4096 + i * 2048 + rb0];
                i32x4 lo = *(const i32x4*)(yb);
                i32x4 hi = *(const i32x4*)(yb + 512);
                i32x8 bv = __builtin_shufflevector(lo, hi, 0, 1, 2, 3, 4, 5, 6, 7);
                acc[t] = __builtin_amdgcn_mfma_scale_f32_32x32x64_f8f6f4(
                    av, bv, acc[t], 0, 0, 0, 127, 0, 127);
            }
        }

        // epilogue: pure fmin (acc IS sq/2)
        float fm[2] = {INF, INF};
        #pragma unroll
        for (int t = 0; t < 2; ++t)
            #pragma unroll
            for (int r = 0; r < 16; ++r) {
                bmin[t][r] = fminf(bmin[t][r], acc[t][r]);
                fm[t]      = fminf(fm[t], acc[t][r]);
            }
        #pragma unroll
        for (int t = 0; t < 2; ++t)
            atomicMin(&fbuf[b][t * 32 + l31],
                      __float_as_uint(fmaxf(fm[t], 0.0f)));
    }
    __syncthreads();  // fbuf atomics from all waves complete

    // flush forward mins (values are sq/2; finalize applies the 2x)
    for (int i = tid; i < BB * 64; i += 256)
        atomicMin(&fwd[(size_t)(i >> 6) * MM + m0 + (i & 63)], fbuf[i >> 6][i & 63]);

    // backward: sqrt(2 * clamp(min sq/2)), block-reduce, one store/block
    float s = 0.0f;
    #pragma unroll
    for (int t = 0; t < 2; ++t)
        #pragma unroll
        for (int r = 0; r < 16; ++r)
            s += sqrtf(2.0f * fmaxf(bmin[t][r], 0.0f));
    #pragma unroll
    for (int off = 32; off; off >>= 1) s += __shfl_down(s, off, 64);
    if (lane == 0) red[wave] = s;
    __syncthreads();
    if (tid == 0) bpart[id] = red[0] + red[1] + red[2] + red[3];
}

// Finalize: 32 blocks x 256 threads. fwd holds min sq/2 -> dist = sqrt(2v).
__global__ __launch_bounds__(256)
void finalize_kernel(const unsigned int* __restrict__ fwd,
                     const float* __restrict__ bpart,
                     float* __restrict__ bsum, float* __restrict__ fsum,
                     unsigned int* __restrict__ counter, float* __restrict__ out) {
    __shared__ float redf[4], redb[4];
    __shared__ int isLast;
    const int tid = threadIdx.x, lane = tid & 63, wave = tid >> 6;
    const int gtid = blockIdx.x * 256 + tid;
    uint4 u = ((const uint4*)fwd)[gtid];
    float sf = sqrtf(2.0f * __uint_as_float(u.x)) + sqrtf(2.0f * __uint_as_float(u.y)) +
               sqrtf(2.0f * __uint_as_float(u.z)) + sqrtf(2.0f * __uint_as_float(u.w));
    float sb = (gtid < 2048) ? bpart[gtid] : 0.0f;   // 2048 main blocks
    #pragma unroll
    for (int off = 32; off; off >>= 1) {
        sf += __shfl_down(sf, off, 64);
        sb += __shfl_down(sb, off, 64);
    }
    if (lane == 0) { redf[wave] = sf; redb[wave] = sb; }
    __syncthreads();
    if (tid == 0) {
        atomicAdd(fsum, redf[0] + redf[1] + redf[2] + redf[3]);
        atomicAdd(bsum, redb[0] + redb[1] + redb[2] + redb[3]);
        __threadfence();
        unsigned int c = atomicAdd(counter, 1u);
        isLast = (c == gridDim.x - 1) ? 1 : 0;
        if (isLast) {
            __threadfence();
            float fs = __hip_atomic_load(fsum, __ATOMIC_RELAXED,
                                         __HIP_MEMORY_SCOPE_AGENT);
            float bs = __hip_atomic_load(bsum, __ATOMIC_RELAXED,
                                         __HIP_MEMORY_SCOPE_AGENT);
            out[0] = fs / (float)(BB * MM) + bs / ((float)NN * (float)MM);
        }
    }
}

extern "C" void kernel_launch(void* const* d_in, const int* in_sizes, int n_in,
                              void* d_out, int out_size, void* d_ws, size_t ws_size,
                              hipStream_t stream) {
    const float* x = (const float*)d_in[0];  // (B,N,D)
    const float* y = (const float*)d_in[1];  // (B,M,D)
    float* out = (float*)d_out;

    char* w = (char*)d_ws;
    unsigned char* xq = (unsigned char*)(w);               // 4 MB fp8 (frag order)
    unsigned char* yq = (unsigned char*)(w + 4194304);     // 4 MB fp8, NEGATED
    float*    x2 = (float*)(w + 8388608);                  // 128 KB (x2/2)
    float*    y2 = (float*)(w + 8519680);                  // 128 KB (y2/2)
    unsigned int* fwd = (unsigned int*)(w + 8650752);      // 128 KB (min sq/2)
    float*    bpart = (float*)(w + 8781824);               // 8 KB (2048 blocks)
    float*    bsum = (float*)(w + 8798208);                // 4 B
    float*    fsum = (float*)(w + 8798212);                // 4 B
    unsigned int* counter = (unsigned int*)(w + 8798216);  // 4 B

    prep_all<<<2048, 256, 0, stream>>>(x, y, xq, yq, x2, y2,
                                       fwd, bsum, fsum, counter);
    chamfer_main<<<2048, 256, 0, stream>>>(xq, yq, x2, y2, fwd, bpart);
    finalize_kernel<<<32, 256, 0, stream>>>(fwd, bpart, bsum, fsum, counter, out);
}

// Round 6
// 112.406 us; speedup vs baseline: 1.2444x; 1.0128x over previous
//
#include <hip/hip_runtime.h>
#include <hip/hip_fp8.h>

#define BB 8
#define NN 4096
#define MM 4096
#define DD 128

typedef float f32x4  __attribute__((ext_vector_type(4)));
typedef float f32x16 __attribute__((ext_vector_type(16)));
typedef int   i32x4  __attribute__((ext_vector_type(4)));
typedef int   i32x8  __attribute__((ext_vector_type(8)));

// ---------------------------------------------------------------------------
// R26: double the TLP of the barrier-free main. R25 evidence: main=43.5us,
// Occ 17.4% (74KB LDS -> 2 blocks/CU -> 2 waves/SIMD), per-batch ~1630
// cyc/SIMD vs ~275 matrix + ~220 VALU floor -> latency-bound, not pipe-bound.
// Fix: halve the block's m-extent (64->32m). y working set = 8 x 4KB = 32KB,
// total LDS ~39KB -> 4 blocks/CU = 16 waves/CU (4 waves/SIMD). Per-wave
// state halves too (acc 16, bmin 16 -> VGPR ~75 < 128 cap of (256,4)).
// Grid 4096 blocks, same balanced XCD patch (1MB x + 2MB y < 4MB XCD L2).
// VALU/batch halves (seed 16 add + 32 fmin) -> VALU floor ~6us; matrix
// ~7.3us is the new leading floor. Staging swizzle = R22's VERIFIED formula
// restricted to one group (unit map re-derived: write (2i+kh)*64+hh*32+row
// == read i*128+kh*64+hh*32+row).
//
// Fixed harness cost seen in R25 counters: 2x 44us fillBufferAligned
// (256MiB ws re-poison) inside the measured window — not controllable.
//
// R19-25 retained: fragment-ordered fp8 (absmax 0), HALF-norms + negated y
// (acc=sq/2), mfma_scale_f32_32x32x64_f8f6f4 identity scale 127, coalesced
// LDS-staged prep, barrier-free batch loop, all-y-staged prologue.
// LESSONS: merged finalize regresses (R11/12/15/16); cooperative launch
// fails (R14); prep transport not the gap (R21); per-batch barriers cost
// ~2x at low occ (R23); 8-wave blocks spill with this state size (R24).
// ---------------------------------------------------------------------------

typedef const __attribute__((address_space(1))) unsigned int* gas_ptr;
typedef __attribute__((address_space(3))) unsigned int* las_ptr;
static __device__ __forceinline__ void gload_lds16(const unsigned char* g,
                                                   unsigned char* l) {
    __builtin_amdgcn_global_load_lds((gas_ptr)g, (las_ptr)l, 16, 0, 0);
}

// Prep v2 (R21, unchanged): 2048 blocks x 256 threads, one 32-row fragment
// group (4KB) per block; coalesced reads -> cvt -> LDS permute -> coalesced
// 16B stores. Also inits fwd/bsum/fsum/counter and writes half-norms.
__global__ __launch_bounds__(256)
void prep_all(const float* __restrict__ x, const float* __restrict__ y,
              unsigned char* __restrict__ xq, unsigned char* __restrict__ yq,
              float* __restrict__ x2, float* __restrict__ y2,
              unsigned int* __restrict__ fwd, float* __restrict__ bsum,
              float* __restrict__ fsum, unsigned int* __restrict__ counter) {
    __shared__ i32x4 lbuf[256];  // 4 KB fragment-ordered staging

    const int tid  = threadIdx.x;
    const int g    = blockIdx.x;
    const int gtid = g * 256 + tid;
    if (gtid < BB * MM) fwd[gtid] = 0x7f800000u;  // +inf bits
    if (gtid == 0) { *bsum = 0.0f; *fsum = 0.0f; *counter = 0u; }

    const int rl = tid >> 3;   // row within group (0..31)
    const int c  = tid & 7;    // 16-float chunk within row (0..7)

    const float* src;
    unsigned char* dst;
    float* sq;
    float sgn;
    int row;
    if (g < 1024) {
        src = x; dst = xq + (size_t)g * 4096; sq = x2; sgn = 1.0f;
        row = g * 32 + rl;
    } else {
        src = y; dst = yq + (size_t)(g - 1024) * 4096; sq = y2; sgn = -1.0f;
        row = (g - 1024) * 32 + rl;
    }

    const f32x4* base = (const f32x4*)(src + (size_t)row * DD + c * 16);
    f32x4 v[4];
    #pragma unroll
    for (int j = 0; j < 4; ++j) v[j] = base[j];

    float s = 0.0f;
    #pragma unroll
    for (int j = 0; j < 4; ++j)
        s += v[j].x * v[j].x + v[j].y * v[j].y + v[j].z * v[j].z + v[j].w * v[j].w;

    i32x4 d;
    #pragma unroll
    for (int j = 0; j < 4; ++j) {
        unsigned int dj = (unsigned int)__builtin_amdgcn_cvt_pk_fp8_f32(
            sgn * v[j].x, sgn * v[j].y, 0, false);
        dj = (unsigned int)__builtin_amdgcn_cvt_pk_fp8_f32(
            sgn * v[j].z, sgn * v[j].w, (int)dj, true);
        d[j] = (int)dj;
    }

    const int lds_off = (c >> 2) * 2048 + ((c >> 1) & 1) * 1024
                      + rl * 32 + (c & 1) * 16;
    *(i32x4*)((char*)lbuf + lds_off) = d;

    #pragma unroll
    for (int m = 4; m; m >>= 1) s += __shfl_xor(s, m, 64);
    if (c == 0) sq[row] = 0.5f * s;

    __syncthreads();
    *(i32x4*)(dst + (size_t)tid * 16) = lbuf[tid];
}

// ---------------------------------------------------------------------------
// Main v6: 4096 blocks (128n x 32m), 4 waves of 32n x 32m, all-y-staged
// prologue, barrier-free batch loop, 16 waves/CU.
// ---------------------------------------------------------------------------
__global__ __launch_bounds__(256, 4)
void chamfer_main(const unsigned char* __restrict__ xq, const unsigned char* __restrict__ yq,
                  const float* __restrict__ x2, const float* __restrict__ y2,
                  unsigned int* __restrict__ fwd, float* __restrict__ bpart) {
    __shared__ float x2s[BB][128];            // 4 KB
    __shared__ float y2s[BB][32];             // 1 KB
    __shared__ unsigned int fbuf[BB][32];     // 1 KB
    __shared__ unsigned char ybuf[BB][4096];  // 32 KB: ALL batches of y-frags
    __shared__ float red[4];

    const int tid   = threadIdx.x;
    const int lane  = tid & 63;
    const int wave  = tid >> 6;    // 0..3
    const int lhalf = lane >> 5;
    const int l31   = lane & 31;

    const int id  = blockIdx.x;
    const int xcd = id & 7;
    const int j   = id >> 3;                   // 0..511
    const int nb  = (xcd >> 1) * 8 + (j & 7);  // 0..31   (128 n each)
    const int mb  = (xcd & 1) * 64 + (j >> 3); // 0..127  (32 m each)
    const int n0b = nb * 128;
    const int n0w = n0b + wave * 32;
    const int m0  = mb * 32;

    // x fragment base (per-wave registers)
    const size_t laneoff = (size_t)lhalf * 1024 + (size_t)l31 * 32;
    const unsigned char* xbase = xq + (size_t)(n0w >> 5) * 4096 + laneoff;

    // y staging, source-swizzled so LDS is dense (R22-verified formula,
    // single group): wave w stages chunk w; lane -> row l31, 16B-half lhalf.
    const size_t ysw = (size_t)(wave >> 1) * 2048 + (size_t)(wave & 1) * 1024
                     + ((size_t)lhalf << 4) + (size_t)l31 * 32;
    const unsigned char* ybase = yq + (size_t)mb * 4096 + ysw;

    // prologue: stage ALL 8 batches of y (1 gload_lds per wave per batch)
    #pragma unroll
    for (int b = 0; b < BB; ++b)
        gload_lds16(ybase + ((size_t)b << 19), &ybuf[b][wave * 1024]);

    i32x4 fx[2][2][2];  // [buf][instr(K64)][16B half]
    auto loadx = [&](int b, int s) {
        const unsigned char* xb = xbase + ((size_t)b << 19);
        #pragma unroll
        for (int i = 0; i < 2; ++i)
            #pragma unroll
            for (int hh = 0; hh < 2; ++hh)
                fx[s][i][hh] = *(const i32x4*)(xb + i * 2048 + hh * 16);
    };
    loadx(0, 0);

    for (int i = tid; i < BB * 128; i += 256)
        x2s[i >> 7][i & 127] = x2[(size_t)(i >> 7) * NN + n0b + (i & 127)];
    {
        int i = tid;  // exactly BB*32 = 256 items
        y2s[i >> 5][i & 31] = y2[(size_t)(i >> 5) * MM + m0 + (i & 31)];
        ((unsigned int*)fbuf)[i] = 0x7f800000u;
    }
    __syncthreads();  // the ONLY barrier before the loop (drains staging)

    const float INF = __builtin_inff();
    float bmin[16];  // running min of acc = sq/2
    #pragma unroll
    for (int r = 0; r < 16; ++r) bmin[r] = INF;

    const int rb0 = lhalf * 1024 + l31 * 16;  // dense y read base

    #pragma unroll 2
    for (int b = 0; b < BB; ++b) {
        const int cur = b & 1;
        if (b < BB - 1) loadx(b + 1, cur ^ 1);  // reg-dbuf, no barrier needed

        // acc seed: (x2+y2)/2 -> MFMA (neg-y fp8) yields acc = sq/2
        // C/D: col = l31, row = (r&3) + 8*(r>>2) + 4*lhalf
        float y2v = y2s[b][l31];
        f32x16 acc;
        #pragma unroll
        for (int q = 0; q < 4; ++q) {
            f32x4 xv = *(const f32x4*)&x2s[b][wave * 32 + lhalf * 4 + q * 8];
            #pragma unroll
            for (int e = 0; e < 4; ++e)
                acc[q * 4 + e] = xv[e] + y2v;
        }

        #pragma unroll
        for (int i = 0; i < 2; ++i) {
            i32x8 av = __builtin_shufflevector(fx[cur][i][0], fx[cur][i][1],
                                               0, 1, 2, 3, 4, 5, 6, 7);
            const unsigned char* yb = &ybuf[b][i * 2048 + rb0];
            i32x4 lo = *(const i32x4*)(yb);
            i32x4 hi = *(const i32x4*)(yb + 512);
            i32x8 bv = __builtin_shufflevector(lo, hi, 0, 1, 2, 3, 4, 5, 6, 7);
            acc = __builtin_amdgcn_mfma_scale_f32_32x32x64_f8f6f4(
                av, bv, acc, 0, 0, 0, 127, 0, 127);
        }

        // epilogue: pure fmin (acc IS sq/2)
        float fm = INF;
        #pragma unroll
        for (int r = 0; r < 16; ++r) {
            bmin[r] = fminf(bmin[r], acc[r]);
            fm      = fminf(fm, acc[r]);
        }
        // clamp >=0 so uint ordering == float ordering; lanes l/l+32 share
        // an address (2-way): no-return ds_min, pipelined
        atomicMin(&fbuf[b][l31], __float_as_uint(fmaxf(fm, 0.0f)));
    }
    __syncthreads();  // fbuf atomics from all waves complete

    // flush forward mins (values are sq/2; finalize applies the 2x)
    {
        int i = tid;  // exactly BB*32 = 256 items
        atomicMin(&fwd[(size_t)(i >> 5) * MM + m0 + (i & 31)], fbuf[i >> 5][i & 31]);
    }

    // backward: sqrt(2 * clamp(min sq/2)), block-reduce, one store/block
    float s = 0.0f;
    #pragma unroll
    for (int r = 0; r < 16; ++r)
        s += sqrtf(2.0f * fmaxf(bmin[r], 0.0f));
    #pragma unroll
    for (int off = 32; off; off >>= 1) s += __shfl_down(s, off, 64);
    if (lane == 0) red[wave] = s;
    __syncthreads();
    if (tid == 0) bpart[id] = red[0] + red[1] + red[2] + red[3];
}

// Finalize: 32 blocks x 256 threads. fwd holds min sq/2 -> dist = sqrt(2v).
__global__ __launch_bounds__(256)
void finalize_kernel(const unsigned int* __restrict__ fwd,
                     const float* __restrict__ bpart,
                     float* __restrict__ bsum, float* __restrict__ fsum,
                     unsigned int* __restrict__ counter, float* __restrict__ out) {
    __shared__ float redf[4], redb[4];
    __shared__ int isLast;
    const int tid = threadIdx.x, lane = tid & 63, wave = tid >> 6;
    const int gtid = blockIdx.x * 256 + tid;
    uint4 u = ((const uint4*)fwd)[gtid];
    float sf = sqrtf(2.0f * __uint_as_float(u.x)) + sqrtf(2.0f * __uint_as_float(u.y)) +
               sqrtf(2.0f * __uint_as_float(u.z)) + sqrtf(2.0f * __uint_as_float(u.w));
    float sb = (gtid < 4096) ? bpart[gtid] : 0.0f;   // 4096 main blocks
    #pragma unroll
    for (int off = 32; off; off >>= 1) {
        sf += __shfl_down(sf, off, 64);
        sb += __shfl_down(sb, off, 64);
    }
    if (lane == 0) { redf[wave] = sf; redb[wave] = sb; }
    __syncthreads();
    if (tid == 0) {
        atomicAdd(fsum, redf[0] + redf[1] + redf[2] + redf[3]);
        atomicAdd(bsum, redb[0] + redb[1] + redb[2] + redb[3]);
        __threadfence();
        unsigned int c = atomicAdd(counter, 1u);
        isLast = (c == gridDim.x - 1) ? 1 : 0;
        if (isLast) {
            __threadfence();
            float fs = __hip_atomic_load(fsum, __ATOMIC_RELAXED,
                                         __HIP_MEMORY_SCOPE_AGENT);
            float bs = __hip_atomic_load(bsum, __ATOMIC_RELAXED,
                                         __HIP_MEMORY_SCOPE_AGENT);
            out[0] = fs / (float)(BB * MM) + bs / ((float)NN * (float)MM);
        }
    }
}

extern "C" void kernel_launch(void* const* d_in, const int* in_sizes, int n_in,
                              void* d_out, int out_size, void* d_ws, size_t ws_size,
                              hipStream_t stream) {
    const float* x = (const float*)d_in[0];  // (B,N,D)
    const float* y = (const float*)d_in[1];  // (B,M,D)
    float* out = (float*)d_out;

    char* w = (char*)d_ws;
    unsigned char* xq = (unsigned char*)(w);               // 4 MB fp8 (frag order)
    unsigned char* yq = (unsigned char*)(w + 4194304);     // 4 MB fp8, NEGATED
    float*    x2 = (float*)(w + 8388608);                  // 128 KB (x2/2)
    float*    y2 = (float*)(w + 8519680);                  // 128 KB (y2/2)
    unsigned int* fwd = (unsigned int*)(w + 8650752);      // 128 KB (min sq/2)
    float*    bpart = (float*)(w + 8781824);               // 16 KB (4096 blocks)
    float*    bsum = (float*)(w + 8798208);                // 4 B
    float*    fsum = (float*)(w + 8798212);                // 4 B
    unsigned int* counter = (unsigned int*)(w + 8798216);  // 4 B

    prep_all<<<2048, 256, 0, stream>>>(x, y, xq, yq, x2, y2,
                                       fwd, bsum, fsum, counter);
    chamfer_main<<<4096, 256, 0, stream>>>(xq, yq, x2, y2, fwd, bpart);
    finalize_kernel<<<32, 256, 0, stream>>>(fwd, bpart, bsum, fsum, counter, out);
}

// Round 7
// 111.192 us; speedup vs baseline: 1.2580x; 1.0109x over previous
//
#include <hip/hip_runtime.h>
#include <hip/hip_fp8.h>

#define BB 8
#define NN 4096
#define MM 4096
#define DD 128

typedef float f32x4  __attribute__((ext_vector_type(4)));
typedef float f32x16 __attribute__((ext_vector_type(16)));
typedef int   i32x4  __attribute__((ext_vector_type(4)));
typedef int   i32x8  __attribute__((ext_vector_type(8)));

// ---------------------------------------------------------------------------
// R27: deepen the x-fragment prefetch pipeline. R26 evidence: main ~42us
// (fell below the 43.7us fill dispatches; total tracks main+~70us fixed),
// i.e. doubling waves/SIMD bought ~1.5us. Little's-law across rounds:
//   R20  8 loads-in-flight/wave, ~11 w/CU -> 19.1 TB/s effective
//   R25  4/wave,  8 w/CU ->  8.8 TB/s
//   R26  4/wave, 16 w/CU -> 15.2 TB/s   (and traffic rose 384->640MB)
// -> the fragment stream is OUTSTANDING-REQUEST latency-bound (fabric
// demonstrated >=19 TB/s, L2 ceiling 34.5). Fix: fx ring-of-3, issue
// loadx(b+2) in-loop -> 8-12 loads in flight/wave (2-3x R26) at 16 w/CU.
// Loop FULLY unrolled so all ring indices are compile-time (runtime-indexed
// ext_vector arrays go to scratch -> R24's 118MB spill disaster).
// VGPR est ~110-120 < 128 cap of (256,4). Spill tripwire: WRITE_SIZE.
//
// Fixed harness cost (R25/R26 counters): multiple 44-48us 256MiB
// fillBufferAligned re-poisons inside the measured window — untouchable.
//
// R19-26 retained: fragment-ordered fp8 (absmax 0), HALF-norms + negated y
// (acc=sq/2), mfma_scale_f32_32x32x64_f8f6f4 identity scale 127, balanced
// per-XCD patch (<4MB XCD L2), coalesced LDS-staged prep, all-y-staged
// prologue, barrier-free batch loop.
// LESSONS: merged finalize regresses (R11/12/15/16); cooperative launch
// fails (R14); prep transport not the gap (R21); per-batch barriers cost
// ~2x at low occ (R23); spills catastrophic (R24); TLP alone doesn't fix
// a depth-1 load pipeline (R26).
// ---------------------------------------------------------------------------

typedef const __attribute__((address_space(1))) unsigned int* gas_ptr;
typedef __attribute__((address_space(3))) unsigned int* las_ptr;
static __device__ __forceinline__ void gload_lds16(const unsigned char* g,
                                                   unsigned char* l) {
    __builtin_amdgcn_global_load_lds((gas_ptr)g, (las_ptr)l, 16, 0, 0);
}

// Prep v2 (R21, unchanged): 2048 blocks x 256 threads, one 32-row fragment
// group (4KB) per block; coalesced reads -> cvt -> LDS permute -> coalesced
// 16B stores. Also inits fwd/bsum/fsum/counter and writes half-norms.
__global__ __launch_bounds__(256)
void prep_all(const float* __restrict__ x, const float* __restrict__ y,
              unsigned char* __restrict__ xq, unsigned char* __restrict__ yq,
              float* __restrict__ x2, float* __restrict__ y2,
              unsigned int* __restrict__ fwd, float* __restrict__ bsum,
              float* __restrict__ fsum, unsigned int* __restrict__ counter) {
    __shared__ i32x4 lbuf[256];  // 4 KB fragment-ordered staging

    const int tid  = threadIdx.x;
    const int g    = blockIdx.x;
    const int gtid = g * 256 + tid;
    if (gtid < BB * MM) fwd[gtid] = 0x7f800000u;  // +inf bits
    if (gtid == 0) { *bsum = 0.0f; *fsum = 0.0f; *counter = 0u; }

    const int rl = tid >> 3;   // row within group (0..31)
    const int c  = tid & 7;    // 16-float chunk within row (0..7)

    const float* src;
    unsigned char* dst;
    float* sq;
    float sgn;
    int row;
    if (g < 1024) {
        src = x; dst = xq + (size_t)g * 4096; sq = x2; sgn = 1.0f;
        row = g * 32 + rl;
    } else {
        src = y; dst = yq + (size_t)(g - 1024) * 4096; sq = y2; sgn = -1.0f;
        row = (g - 1024) * 32 + rl;
    }

    const f32x4* base = (const f32x4*)(src + (size_t)row * DD + c * 16);
    f32x4 v[4];
    #pragma unroll
    for (int j = 0; j < 4; ++j) v[j] = base[j];

    float s = 0.0f;
    #pragma unroll
    for (int j = 0; j < 4; ++j)
        s += v[j].x * v[j].x + v[j].y * v[j].y + v[j].z * v[j].z + v[j].w * v[j].w;

    i32x4 d;
    #pragma unroll
    for (int j = 0; j < 4; ++j) {
        unsigned int dj = (unsigned int)__builtin_amdgcn_cvt_pk_fp8_f32(
            sgn * v[j].x, sgn * v[j].y, 0, false);
        dj = (unsigned int)__builtin_amdgcn_cvt_pk_fp8_f32(
            sgn * v[j].z, sgn * v[j].w, (int)dj, true);
        d[j] = (int)dj;
    }

    const int lds_off = (c >> 2) * 2048 + ((c >> 1) & 1) * 1024
                      + rl * 32 + (c & 1) * 16;
    *(i32x4*)((char*)lbuf + lds_off) = d;

    #pragma unroll
    for (int m = 4; m; m >>= 1) s += __shfl_xor(s, m, 64);
    if (c == 0) sq[row] = 0.5f * s;

    __syncthreads();
    *(i32x4*)(dst + (size_t)tid * 16) = lbuf[tid];
}

// ---------------------------------------------------------------------------
// Main v7: 4096 blocks (128n x 32m), 4 waves of 32n x 32m, all-y-staged
// prologue, barrier-free FULLY-UNROLLED batch loop, fx ring-of-3 prefetch.
// ---------------------------------------------------------------------------
__global__ __launch_bounds__(256, 4)
void chamfer_main(const unsigned char* __restrict__ xq, const unsigned char* __restrict__ yq,
                  const float* __restrict__ x2, const float* __restrict__ y2,
                  unsigned int* __restrict__ fwd, float* __restrict__ bpart) {
    __shared__ float x2s[BB][128];            // 4 KB
    __shared__ float y2s[BB][32];             // 1 KB
    __shared__ unsigned int fbuf[BB][32];     // 1 KB
    __shared__ unsigned char ybuf[BB][4096];  // 32 KB: ALL batches of y-frags
    __shared__ float red[4];

    const int tid   = threadIdx.x;
    const int lane  = tid & 63;
    const int wave  = tid >> 6;    // 0..3
    const int lhalf = lane >> 5;
    const int l31   = lane & 31;

    const int id  = blockIdx.x;
    const int xcd = id & 7;
    const int j   = id >> 3;                   // 0..511
    const int nb  = (xcd >> 1) * 8 + (j & 7);  // 0..31   (128 n each)
    const int mb  = (xcd & 1) * 64 + (j >> 3); // 0..127  (32 m each)
    const int n0b = nb * 128;
    const int n0w = n0b + wave * 32;
    const int m0  = mb * 32;

    // x fragment base (per-wave registers)
    const size_t laneoff = (size_t)lhalf * 1024 + (size_t)l31 * 32;
    const unsigned char* xbase = xq + (size_t)(n0w >> 5) * 4096 + laneoff;

    // y staging, source-swizzled so LDS is dense (R22-verified formula,
    // single group): wave w stages chunk w; lane -> row l31, 16B-half lhalf.
    const size_t ysw = (size_t)(wave >> 1) * 2048 + (size_t)(wave & 1) * 1024
                     + ((size_t)lhalf << 4) + (size_t)l31 * 32;
    const unsigned char* ybase = yq + (size_t)mb * 4096 + ysw;

    // prologue: stage ALL 8 batches of y (1 gload_lds per wave per batch)
    #pragma unroll
    for (int b = 0; b < BB; ++b)
        gload_lds16(ybase + ((size_t)b << 19), &ybuf[b][wave * 1024]);

    i32x4 fx[3][2][2];  // ring-of-3 [buf][instr(K64)][16B half]
    auto loadx = [&](int b, int s) {
        const unsigned char* xb = xbase + ((size_t)b << 19);
        #pragma unroll
        for (int i = 0; i < 2; ++i)
            #pragma unroll
            for (int hh = 0; hh < 2; ++hh)
                fx[s][i][hh] = *(const i32x4*)(xb + i * 2048 + hh * 16);
    };
    loadx(0, 0);   // depth-2 prologue burst
    loadx(1, 1);

    for (int i = tid; i < BB * 128; i += 256)
        x2s[i >> 7][i & 127] = x2[(size_t)(i >> 7) * NN + n0b + (i & 127)];
    {
        int i = tid;  // exactly BB*32 = 256 items
        y2s[i >> 5][i & 31] = y2[(size_t)(i >> 5) * MM + m0 + (i & 31)];
        ((unsigned int*)fbuf)[i] = 0x7f800000u;
    }
    __syncthreads();  // the ONLY barrier before the loop (drains staging)

    const float INF = __builtin_inff();
    float bmin[16];  // running min of acc = sq/2
    #pragma unroll
    for (int r = 0; r < 16; ++r) bmin[r] = INF;

    const int rb0 = lhalf * 1024 + l31 * 16;  // dense y read base

    #pragma unroll   // FULL unroll: ring indices must be compile-time
    for (int b = 0; b < BB; ++b) {
        const int cur = b % 3;
        if (b + 2 < BB) loadx(b + 2, (b + 2) % 3);  // 8+ loads in flight

        // acc seed: (x2+y2)/2 -> MFMA (neg-y fp8) yields acc = sq/2
        // C/D: col = l31, row = (r&3) + 8*(r>>2) + 4*lhalf
        float y2v = y2s[b][l31];
        f32x16 acc;
        #pragma unroll
        for (int q = 0; q < 4; ++q) {
            f32x4 xv = *(const f32x4*)&x2s[b][wave * 32 + lhalf * 4 + q * 8];
            #pragma unroll
            for (int e = 0; e < 4; ++e)
                acc[q * 4 + e] = xv[e] + y2v;
        }

        #pragma unroll
        for (int i = 0; i < 2; ++i) {
            i32x8 av = __builtin_shufflevector(fx[cur][i][0], fx[cur][i][1],
                                               0, 1, 2, 3, 4, 5, 6, 7);
            const unsigned char* yb = &ybuf[b][i * 2048 + rb0];
            i32x4 lo = *(const i32x4*)(yb);
            i32x4 hi = *(const i32x4*)(yb + 512);
            i32x8 bv = __builtin_shufflevector(lo, hi, 0, 1, 2, 3, 4, 5, 6, 7);
            acc = __builtin_amdgcn_mfma_scale_f32_32x32x64_f8f6f4(
                av, bv, acc, 0, 0, 0, 127, 0, 127);
        }

        // epilogue: pure fmin (acc IS sq/2)
        float fm = INF;
        #pragma unroll
        for (int r = 0; r < 16; ++r) {
            bmin[r] = fminf(bmin[r], acc[r]);
            fm      = fminf(fm, acc[r]);
        }
        // clamp >=0 so uint ordering == float ordering; lanes l/l+32 share
        // an address (2-way): no-return ds_min, pipelined
        atomicMin(&fbuf[b][l31], __float_as_uint(fmaxf(fm, 0.0f)));
    }
    __syncthreads();  // fbuf atomics from all waves complete

    // flush forward mins (values are sq/2; finalize applies the 2x)
    {
        int i = tid;  // exactly BB*32 = 256 items
        atomicMin(&fwd[(size_t)(i >> 5) * MM + m0 + (i & 31)], fbuf[i >> 5][i & 31]);
    }

    // backward: sqrt(2 * clamp(min sq/2)), block-reduce, one store/block
    float s = 0.0f;
    #pragma unroll
    for (int r = 0; r < 16; ++r)
        s += sqrtf(2.0f * fmaxf(bmin[r], 0.0f));
    #pragma unroll
    for (int off = 32; off; off >>= 1) s += __shfl_down(s, off, 64);
    if (lane == 0) red[wave] = s;
    __syncthreads();
    if (tid == 0) bpart[id] = red[0] + red[1] + red[2] + red[3];
}

// Finalize: 32 blocks x 256 threads. fwd holds min sq/2 -> dist = sqrt(2v).
__global__ __launch_bounds__(256)
void finalize_kernel(const unsigned int* __restrict__ fwd,
                     const float* __restrict__ bpart,
                     float* __restrict__ bsum, float* __restrict__ fsum,
                     unsigned int* __restrict__ counter, float* __restrict__ out) {
    __shared__ float redf[4], redb[4];
    __shared__ int isLast;
    const int tid = threadIdx.x, lane = tid & 63, wave = tid >> 6;
    const int gtid = blockIdx.x * 256 + tid;
    uint4 u = ((const uint4*)fwd)[gtid];
    float sf = sqrtf(2.0f * __uint_as_float(u.x)) + sqrtf(2.0f * __uint_as_float(u.y)) +
               sqrtf(2.0f * __uint_as_float(u.z)) + sqrtf(2.0f * __uint_as_float(u.w));
    float sb = (gtid < 4096) ? bpart[gtid] : 0.0f;   // 4096 main blocks
    #pragma unroll
    for (int off = 32; off; off >>= 1) {
        sf += __shfl_down(sf, off, 64);
        sb += __shfl_down(sb, off, 64);
    }
    if (lane == 0) { redf[wave] = sf; redb[wave] = sb; }
    __syncthreads();
    if (tid == 0) {
        atomicAdd(fsum, redf[0] + redf[1] + redf[2] + redf[3]);
        atomicAdd(bsum, redb[0] + redb[1] + redb[2] + redb[3]);
        __threadfence();
        unsigned int c = atomicAdd(counter, 1u);
        isLast = (c == gridDim.x - 1) ? 1 : 0;
        if (isLast) {
            __threadfence();
            float fs = __hip_atomic_load(fsum, __ATOMIC_RELAXED,
                                         __HIP_MEMORY_SCOPE_AGENT);
            float bs = __hip_atomic_load(bsum, __ATOMIC_RELAXED,
                                         __HIP_MEMORY_SCOPE_AGENT);
            out[0] = fs / (float)(BB * MM) + bs / ((float)NN * (float)MM);
        }
    }
}

extern "C" void kernel_launch(void* const* d_in, const int* in_sizes, int n_in,
                              void* d_out, int out_size, void* d_ws, size_t ws_size,
                              hipStream_t stream) {
    const float* x = (const float*)d_in[0];  // (B,N,D)
    const float* y = (const float*)d_in[1];  // (B,M,D)
    float* out = (float*)d_out;

    char* w = (char*)d_ws;
    unsigned char* xq = (unsigned char*)(w);               // 4 MB fp8 (frag order)
    unsigned char* yq = (unsigned char*)(w + 4194304);     // 4 MB fp8, NEGATED
    float*    x2 = (float*)(w + 8388608);                  // 128 KB (x2/2)
    float*    y2 = (float*)(w + 8519680);                  // 128 KB (y2/2)
    unsigned int* fwd = (unsigned int*)(w + 8650752);      // 128 KB (min sq/2)
    float*    bpart = (float*)(w + 8781824);               // 16 KB (4096 blocks)
    float*    bsum = (float*)(w + 8798208);                // 4 B
    float*    fsum = (float*)(w + 8798212);                // 4 B
    unsigned int* counter = (unsigned int*)(w + 8798216);  // 4 B

    prep_all<<<2048, 256, 0, stream>>>(x, y, xq, yq, x2, y2,
                                       fwd, bsum, fsum, counter);
    chamfer_main<<<4096, 256, 0, stream>>>(xq, yq, x2, y2, fwd, bpart);
    finalize_kernel<<<32, 256, 0, stream>>>(fwd, bpart, bsum, fsum, counter, out);
}